// Round 1
// baseline (1095.279 us; speedup 1.0000x reference)
//
#include <hip/hip_runtime.h>
#include <cstdint>
#include <cstddef>

// Problem constants
#define B_ 8
#define C_ 512
#define L_ 4096
#define M_ 2048   // L/2 (pooled keys)
#define CK_ 64    // C/8
#define CV_ 256   // C/2
#define QT 8      // queries per attention block

// ---------------------------------------------------------------------------
// Kernel A: channel projection  out[b,k,j] = sum_c W[k,c] * x[b,c,j]
//   POOL=1: maxpool2 over last axis (j indexes pooled output, reads 2j,2j+1)
//   TRANS=1: write transposed as out[b,j,k]  (used for g -> gT[b,m,v])
//   Tiles 16 output rows per block (W rows staged in LDS) so each x element
//   is loaded once per 16 rows instead of once per row.
// ---------------------------------------------------------------------------
template <int POOL, int TRANS>
__global__ __launch_bounds__(256) void proj_kernel(const float* __restrict__ W,
                                                   const float* __restrict__ x,
                                                   float* __restrict__ out,
                                                   int K) {
    __shared__ float wsm[16][C_];  // 32 KB
    const int b  = blockIdx.z;
    const int k0 = blockIdx.y * 16;
    const int t  = threadIdx.x;
    const int j  = blockIdx.x * 256 + t;

    // stage 16 W rows: 16*512 = 8192 elems, 32 per thread, coalesced
#pragma unroll
    for (int i = 0; i < 32; ++i) {
        int f = i * 256 + t;
        wsm[f >> 9][f & 511] = W[(size_t)(k0 + (f >> 9)) * C_ + (f & 511)];
    }
    __syncthreads();

    const float* xb = x + (size_t)b * C_ * L_;
    float a0[16];
#pragma unroll
    for (int kk = 0; kk < 16; ++kk) a0[kk] = 0.f;

    if (POOL) {
        float a1[16];
#pragma unroll
        for (int kk = 0; kk < 16; ++kk) a1[kk] = 0.f;
        for (int c = 0; c < C_; ++c) {
            float2 v = *reinterpret_cast<const float2*>(xb + (size_t)c * L_ + 2 * j);
#pragma unroll
            for (int kk = 0; kk < 16; ++kk) {
                float w = wsm[kk][c];
                a0[kk] = fmaf(w, v.x, a0[kk]);
                a1[kk] = fmaf(w, v.y, a1[kk]);
            }
        }
#pragma unroll
        for (int kk = 0; kk < 16; ++kk) a0[kk] = fmaxf(a0[kk], a1[kk]);
    } else {
        for (int c = 0; c < C_; ++c) {
            float v = xb[(size_t)c * L_ + j];
#pragma unroll
            for (int kk = 0; kk < 16; ++kk) a0[kk] = fmaf(wsm[kk][c], v, a0[kk]);
        }
    }

    const int Lout = POOL ? M_ : L_;
    if (TRANS) {
        // out[b, j, k0..k0+15] : 64B contiguous per thread -> 4x float4
        float* op = out + ((size_t)b * Lout + j) * K + k0;
#pragma unroll
        for (int kk = 0; kk < 16; kk += 4) {
            float4 v = make_float4(a0[kk], a0[kk + 1], a0[kk + 2], a0[kk + 3]);
            *reinterpret_cast<float4*>(op + kk) = v;
        }
    } else {
#pragma unroll
        for (int kk = 0; kk < 16; ++kk)
            out[((size_t)b * K + k0 + kk) * Lout + j] = a0[kk];
    }
}

// ---------------------------------------------------------------------------
// Kernel B: fused scores + softmax + PV for a tile of QT=8 queries.
//   phase 1: sc[q][i] = sum_k theta[b,k,q0+q] * phi[b,k,m], m = i*256 + t
//            (phi reads coalesced across t); block softmax over m in
//            registers + shuffle/LDS reduce; normalized beta -> 64 KB LDS.
//   phase 2: o_inT[b,l,v] = sum_m beta[l,m] * gT[b,m,v]
//            thread owns v-quad (4*vg..), m-stripe ms; gT float4 coalesced;
//            cross-stripe reduce through LDS (beta_s reused as scratch).
// ---------------------------------------------------------------------------
__global__ __launch_bounds__(256) void attn_kernel(const float* __restrict__ theta,
                                                   const float* __restrict__ phi,
                                                   const float* __restrict__ gT,
                                                   float* __restrict__ o_inT) {
    __shared__ float beta_s[QT * M_];   // 64 KB (reused as reduce scratch)
    __shared__ float theta_s[QT][CK_];  // 2 KB
    __shared__ float red_s[2][4][QT];

    const int b    = blockIdx.y;
    const int q0   = blockIdx.x * QT;
    const int t    = threadIdx.x;
    const int lane = t & 63;
    const int wid  = t >> 6;

    // stage theta for the 8 queries
    for (int f = t; f < QT * CK_; f += 256) {
        int q = f >> 6, k = f & 63;
        theta_s[q][k] = theta[((size_t)b * CK_ + k) * L_ + q0 + q];
    }
    __syncthreads();

    // ---- phase 1: scores ----
    float sc[QT][8];
#pragma unroll
    for (int q = 0; q < QT; ++q)
#pragma unroll
        for (int i = 0; i < 8; ++i) sc[q][i] = 0.f;

    const float* phib = phi + (size_t)b * CK_ * M_ + t;
    for (int k = 0; k < CK_; ++k) {
        float th[QT];
#pragma unroll
        for (int q = 0; q < QT; ++q) th[q] = theta_s[q][k];
        const float* pr = phib + (size_t)k * M_;
#pragma unroll
        for (int i = 0; i < 8; ++i) {
            float p = pr[i * 256];
#pragma unroll
            for (int q = 0; q < QT; ++q) sc[q][i] = fmaf(th[q], p, sc[q][i]);
        }
    }

    // ---- softmax: max ----
    float lm[QT];
#pragma unroll
    for (int q = 0; q < QT; ++q) {
        lm[q] = -3.0e38f;
#pragma unroll
        for (int i = 0; i < 8; ++i) lm[q] = fmaxf(lm[q], sc[q][i]);
    }
#pragma unroll
    for (int o = 1; o < 64; o <<= 1)
#pragma unroll
        for (int q = 0; q < QT; ++q) lm[q] = fmaxf(lm[q], __shfl_xor(lm[q], o));
    if (lane == 0) {
#pragma unroll
        for (int q = 0; q < QT; ++q) red_s[0][wid][q] = lm[q];
    }
    __syncthreads();
    float gm[QT];
#pragma unroll
    for (int q = 0; q < QT; ++q)
        gm[q] = fmaxf(fmaxf(red_s[0][0][q], red_s[0][1][q]),
                      fmaxf(red_s[0][2][q], red_s[0][3][q]));

    // ---- softmax: exp + sum ----
    float ls[QT];
#pragma unroll
    for (int q = 0; q < QT; ++q) ls[q] = 0.f;
#pragma unroll
    for (int q = 0; q < QT; ++q)
#pragma unroll
        for (int i = 0; i < 8; ++i) {
            float e = __expf(sc[q][i] - gm[q]);
            sc[q][i] = e;
            ls[q] += e;
        }
#pragma unroll
    for (int o = 1; o < 64; o <<= 1)
#pragma unroll
        for (int q = 0; q < QT; ++q) ls[q] += __shfl_xor(ls[q], o);
    if (lane == 0) {
#pragma unroll
        for (int q = 0; q < QT; ++q) red_s[1][wid][q] = ls[q];
    }
    __syncthreads();
    float inv[QT];
#pragma unroll
    for (int q = 0; q < QT; ++q)
        inv[q] = 1.f / (red_s[1][0][q] + red_s[1][1][q] + red_s[1][2][q] + red_s[1][3][q]);

    // store normalized beta
#pragma unroll
    for (int q = 0; q < QT; ++q)
#pragma unroll
        for (int i = 0; i < 8; ++i) beta_s[q * M_ + i * 256 + t] = sc[q][i] * inv[q];
    __syncthreads();

    // ---- phase 2: PV ----
    const int vg = t & 63;  // v = 4*vg .. 4*vg+3
    const int ms = t >> 6;  // m-stripe: m = 4*mi + ms
    float acc[QT][4];
#pragma unroll
    for (int q = 0; q < QT; ++q)
#pragma unroll
        for (int i = 0; i < 4; ++i) acc[q][i] = 0.f;

    const float* gTb = gT + (size_t)b * M_ * CV_ + 4 * vg;
    for (int mi = 0; mi < M_ / 4; ++mi) {
        int m = mi * 4 + ms;
        float4 gv = *reinterpret_cast<const float4*>(gTb + (size_t)m * CV_);
#pragma unroll
        for (int q = 0; q < QT; ++q) {
            float bq = beta_s[q * M_ + m];  // broadcast
            acc[q][0] = fmaf(bq, gv.x, acc[q][0]);
            acc[q][1] = fmaf(bq, gv.y, acc[q][1]);
            acc[q][2] = fmaf(bq, gv.z, acc[q][2]);
            acc[q][3] = fmaf(bq, gv.w, acc[q][3]);
        }
    }
    __syncthreads();  // all beta reads done before scratch reuse

    float* scratch = beta_s;  // 256*33 = 8448 floats <= 16384 available
#pragma unroll
    for (int q = 0; q < QT; ++q)
#pragma unroll
        for (int i = 0; i < 4; ++i) scratch[t * 33 + q * 4 + i] = acc[q][i];
    __syncthreads();

    if (t < 64) {
#pragma unroll
        for (int q = 0; q < QT; ++q) {
            float4 o;
            o.x = scratch[t * 33 + q * 4 + 0] + scratch[(t + 64) * 33 + q * 4 + 0] +
                  scratch[(t + 128) * 33 + q * 4 + 0] + scratch[(t + 192) * 33 + q * 4 + 0];
            o.y = scratch[t * 33 + q * 4 + 1] + scratch[(t + 64) * 33 + q * 4 + 1] +
                  scratch[(t + 128) * 33 + q * 4 + 1] + scratch[(t + 192) * 33 + q * 4 + 1];
            o.z = scratch[t * 33 + q * 4 + 2] + scratch[(t + 64) * 33 + q * 4 + 2] +
                  scratch[(t + 128) * 33 + q * 4 + 2] + scratch[(t + 192) * 33 + q * 4 + 2];
            o.w = scratch[t * 33 + q * 4 + 3] + scratch[(t + 64) * 33 + q * 4 + 3] +
                  scratch[(t + 128) * 33 + q * 4 + 3] + scratch[(t + 192) * 33 + q * 4 + 3];
            *reinterpret_cast<float4*>(o_inT + ((size_t)b * L_ + q0 + q) * CV_ + 4 * t) = o;
        }
    }
}

// ---------------------------------------------------------------------------
// Kernel C: out[b,oc,l] = gamma * sum_v W_o[oc,v] * o_inT[b,l,v] + x[b,oc,l]
//   64x64 output tile, K=256 in 4 LDS-staged tiles, 4x4 per thread.
// ---------------------------------------------------------------------------
__global__ __launch_bounds__(256) void out_kernel(const float* __restrict__ Wo,
                                                  const float* __restrict__ o_inT,
                                                  const float* __restrict__ x,
                                                  const float* __restrict__ gamma_p,
                                                  float* __restrict__ out) {
    __shared__ float wt[64][65];
    __shared__ float ot[64][65];
    const int b   = blockIdx.z;
    const int oc0 = blockIdx.y * 64;
    const int l0  = blockIdx.x * 64;
    const int t   = threadIdx.x;
    const int tx  = t & 15;   // l-group
    const int ty  = t >> 4;   // oc-group

    float acc[4][4];
#pragma unroll
    for (int i = 0; i < 4; ++i)
#pragma unroll
        for (int j = 0; j < 4; ++j) acc[i][j] = 0.f;

    for (int k0 = 0; k0 < CV_; k0 += 64) {
#pragma unroll
        for (int i = 0; i < 16; ++i) {
            int f = i * 256 + t;
            int r = f >> 6, c = f & 63;
            wt[r][c] = Wo[(size_t)(oc0 + r) * CV_ + k0 + c];
            ot[r][c] = o_inT[((size_t)b * L_ + l0 + r) * CV_ + k0 + c];
        }
        __syncthreads();
        for (int k = 0; k < 64; ++k) {
            float a[4], bb[4];
#pragma unroll
            for (int i = 0; i < 4; ++i) a[i] = wt[ty * 4 + i][k];
#pragma unroll
            for (int j = 0; j < 4; ++j) bb[j] = ot[tx * 4 + j][k];
#pragma unroll
            for (int i = 0; i < 4; ++i)
#pragma unroll
                for (int j = 0; j < 4; ++j) acc[i][j] = fmaf(a[i], bb[j], acc[i][j]);
        }
        __syncthreads();
    }

    const float gamma = *gamma_p;
#pragma unroll
    for (int i = 0; i < 4; ++i) {
        int oc = oc0 + ty * 4 + i;
        const float* xr = x + ((size_t)b * C_ + oc) * L_ + l0 + tx * 4;
        float4 xv = *reinterpret_cast<const float4*>(xr);
        float4 o;
        o.x = fmaf(gamma, acc[i][0], xv.x);
        o.y = fmaf(gamma, acc[i][1], xv.y);
        o.z = fmaf(gamma, acc[i][2], xv.z);
        o.w = fmaf(gamma, acc[i][3], xv.w);
        *reinterpret_cast<float4*>(out + ((size_t)b * C_ + oc) * L_ + l0 + tx * 4) = o;
    }
}

// ---------------------------------------------------------------------------
extern "C" void kernel_launch(void* const* d_in, const int* in_sizes, int n_in,
                              void* d_out, int out_size, void* d_ws, size_t ws_size,
                              hipStream_t stream) {
    const float* x       = (const float*)d_in[0];
    const float* W_theta = (const float*)d_in[1];
    const float* W_phi   = (const float*)d_in[2];
    const float* W_g     = (const float*)d_in[3];
    const float* W_o     = (const float*)d_in[4];
    const float* gamma   = (const float*)d_in[5];
    float* out = (float*)d_out;

    // workspace carve (floats): theta | phi | gT | o_inT  = 60 MiB total
    float* ws    = (float*)d_ws;
    float* theta = ws;                                   // [B][CK][L]
    float* phi   = theta + (size_t)B_ * CK_ * L_;        // [B][CK][M]
    float* gT    = phi + (size_t)B_ * CK_ * M_;          // [B][M][CV]
    float* o_inT = gT + (size_t)B_ * M_ * CV_;           // [B][L][CV]

    proj_kernel<0, 0><<<dim3(L_ / 256, CK_ / 16, B_), 256, 0, stream>>>(W_theta, x, theta, CK_);
    proj_kernel<1, 0><<<dim3(M_ / 256, CK_ / 16, B_), 256, 0, stream>>>(W_phi, x, phi, CK_);
    proj_kernel<1, 1><<<dim3(M_ / 256, CV_ / 16, B_), 256, 0, stream>>>(W_g, x, gT, CV_);
    attn_kernel<<<dim3(L_ / QT, B_), 256, 0, stream>>>(theta, phi, gT, o_inT);
    out_kernel<<<dim3(L_ / 64, C_ / 64, B_), 256, 0, stream>>>(W_o, o_inT, x, gamma, out);
}

// Round 2
// 649.825 us; speedup vs baseline: 1.6855x; 1.6855x over previous
//
#include <hip/hip_runtime.h>
#include <cstdint>
#include <cstddef>

// Problem constants
#define B_ 8
#define C_ 512
#define L_ 4096
#define M_ 2048   // L/2 (pooled keys)
#define CK_ 64    // C/8
#define CV_ 256   // C/2

typedef _Float16 f16;
typedef _Float16 f16x8 __attribute__((ext_vector_type(8)));
typedef _Float16 f16x4 __attribute__((ext_vector_type(4)));
typedef float f32x4 __attribute__((ext_vector_type(4)));

#define MFMA16(A, Bv, Cv) __builtin_amdgcn_mfma_f32_16x16x32_f16(A, Bv, Cv, 0, 0, 0)

// ---------------------------------------------------------------------------
// Kernel A: channel projection (fp32 math, f16 output in MFMA layout)
//   POOL=1: maxpool2 over last axis. TRANS=1: write out[b,j,k] (seq-major).
// ---------------------------------------------------------------------------
template <int POOL, int TRANS>
__global__ __launch_bounds__(256) void proj_kernel(const float* __restrict__ W,
                                                   const float* __restrict__ x,
                                                   f16* __restrict__ out,
                                                   int K) {
    __shared__ float wsm[16][C_];  // 32 KB
    const int b  = blockIdx.z;
    const int k0 = blockIdx.y * 16;
    const int t  = threadIdx.x;
    const int j  = blockIdx.x * 256 + t;

#pragma unroll
    for (int i = 0; i < 32; ++i) {
        int f = i * 256 + t;
        wsm[f >> 9][f & 511] = W[(size_t)(k0 + (f >> 9)) * C_ + (f & 511)];
    }
    __syncthreads();

    const float* xb = x + (size_t)b * C_ * L_;
    float a0[16];
#pragma unroll
    for (int kk = 0; kk < 16; ++kk) a0[kk] = 0.f;

    if (POOL) {
        float a1[16];
#pragma unroll
        for (int kk = 0; kk < 16; ++kk) a1[kk] = 0.f;
        for (int c = 0; c < C_; ++c) {
            float2 v = *reinterpret_cast<const float2*>(xb + (size_t)c * L_ + 2 * j);
#pragma unroll
            for (int kk = 0; kk < 16; ++kk) {
                float w = wsm[kk][c];
                a0[kk] = fmaf(w, v.x, a0[kk]);
                a1[kk] = fmaf(w, v.y, a1[kk]);
            }
        }
#pragma unroll
        for (int kk = 0; kk < 16; ++kk) a0[kk] = fmaxf(a0[kk], a1[kk]);
    } else {
        for (int c = 0; c < C_; ++c) {
            float v = xb[(size_t)c * L_ + j];
#pragma unroll
            for (int kk = 0; kk < 16; ++kk) a0[kk] = fmaf(wsm[kk][c], v, a0[kk]);
        }
    }

    const int Lout = POOL ? M_ : L_;
    if (TRANS) {
        f16* op = out + ((size_t)b * Lout + j) * K + k0;
        f16x8 v0, v1;
#pragma unroll
        for (int kk = 0; kk < 8; ++kk) { v0[kk] = (f16)a0[kk]; v1[kk] = (f16)a0[kk + 8]; }
        *reinterpret_cast<f16x8*>(op)     = v0;
        *reinterpret_cast<f16x8*>(op + 8) = v1;
    } else {
#pragma unroll
        for (int kk = 0; kk < 16; ++kk)
            out[((size_t)b * K + k0 + kk) * Lout + j] = (f16)a0[kk];
    }
}

// ---------------------------------------------------------------------------
// Kernel W: fp32 -> f16 convert for W_o
// ---------------------------------------------------------------------------
__global__ __launch_bounds__(256) void cvt_kernel(const float* __restrict__ in,
                                                  f16* __restrict__ out, int n) {
    int i = blockIdx.x * 256 + threadIdx.x;
    if (i < n) out[i] = (f16)in[i];
}

// ---------------------------------------------------------------------------
// Kernel B: MFMA attention. Block = 16 queries, 4 waves.
//   1a: S^T[m,q] = mfma(K, Q) per 16-m chunk; raw f16 scores -> LDS (swizzled);
//       running row-max per q (shfl_xor 16/32 + LDS reduce).
//   1b: re-read, exp(s - max), write back, accumulate row sum.
//   PV: O[q,v] += mfma(P_frag, V_frag) over 64 m-steps; normalize in epilogue.
// ---------------------------------------------------------------------------
__global__ __launch_bounds__(256) void attn_mfma(const f16* __restrict__ thetaT,
                                                 const f16* __restrict__ phiT,
                                                 const f16* __restrict__ gh,
                                                 f16* __restrict__ o_inT) {
    __shared__ __align__(16) f16 P[16 * 2048];  // 64 KB
    __shared__ float redmax[4][16];
    __shared__ float redsum[4][16];
    __shared__ float linv[16];

    const int b    = blockIdx.y;
    const int q0   = blockIdx.x * 16;
    const int t    = threadIdx.x;
    const int wid  = t >> 6;
    const int lane = t & 63;
    const int lq   = lane & 15;
    const int g    = lane >> 4;
    const int swz  = (lq & 7) << 3;  // XOR on half-index bits 3..5 (byte 4..6)

    // Q as B-operand: lane holds Q[q=lq][ck = 8g+i (+32)]
    const f16* qp = thetaT + ((size_t)b * L_ + q0 + lq) * CK_ + 8 * g;
    const f16x8 Q0 = *reinterpret_cast<const f16x8*>(qp);
    const f16x8 Q1 = *reinterpret_cast<const f16x8*>(qp + 32);

    // ---- phase 1a: raw scores + row max ----
    float rm = -3.0e38f;
    const f16* kp = phiT + (size_t)b * M_ * CK_;
    for (int mc = 0; mc < 32; ++mc) {
        const int mb = wid * 512 + mc * 16;
        const f16* kr = kp + (size_t)(mb + lq) * CK_ + 8 * g;
        f16x8 K0 = *reinterpret_cast<const f16x8*>(kr);
        f16x8 K1 = *reinterpret_cast<const f16x8*>(kr + 32);
        f32x4 s = {0.f, 0.f, 0.f, 0.f};
        s = MFMA16(K0, Q0, s);   // S^T[m = mb+4g+r][q = lq]
        s = MFMA16(K1, Q1, s);
        rm = fmaxf(rm, fmaxf(fmaxf(s[0], s[1]), fmaxf(s[2], s[3])));
        f16x4 pk;
        pk[0] = (f16)s[0]; pk[1] = (f16)s[1]; pk[2] = (f16)s[2]; pk[3] = (f16)s[3];
        const int idx = (lq * 2048 + mb + 4 * g) ^ swz;
        *reinterpret_cast<f16x4*>(&P[idx]) = pk;
    }
    rm = fmaxf(rm, __shfl_xor(rm, 16));
    rm = fmaxf(rm, __shfl_xor(rm, 32));
    if (lane < 16) redmax[wid][lane] = rm;
    __syncthreads();
    const float gm = fmaxf(fmaxf(redmax[0][lq], redmax[1][lq]),
                           fmaxf(redmax[2][lq], redmax[3][lq]));

    // ---- phase 1b: exp + row sum ----
    float rs = 0.f;
    for (int mc = 0; mc < 32; ++mc) {
        const int mb = wid * 512 + mc * 16;
        const int idx = (lq * 2048 + mb + 4 * g) ^ swz;
        f16x4 pk = *reinterpret_cast<f16x4*>(&P[idx]);
        float e0 = __expf((float)pk[0] - gm);
        float e1 = __expf((float)pk[1] - gm);
        float e2 = __expf((float)pk[2] - gm);
        float e3 = __expf((float)pk[3] - gm);
        rs += (e0 + e1) + (e2 + e3);
        pk[0] = (f16)e0; pk[1] = (f16)e1; pk[2] = (f16)e2; pk[3] = (f16)e3;
        *reinterpret_cast<f16x4*>(&P[idx]) = pk;
    }
    rs += __shfl_xor(rs, 16);
    rs += __shfl_xor(rs, 32);
    if (lane < 16) redsum[wid][lane] = rs;
    __syncthreads();
    if (t < 16) linv[t] = 1.f / (redsum[0][t] + redsum[1][t] + redsum[2][t] + redsum[3][t]);
    __syncthreads();

    // ---- PV: wave owns v-range [wid*64, wid*64+64) ----
    f32x4 acc[4] = {{0.f, 0.f, 0.f, 0.f}, {0.f, 0.f, 0.f, 0.f},
                    {0.f, 0.f, 0.f, 0.f}, {0.f, 0.f, 0.f, 0.f}};
    const f16* gb = gh + ((size_t)b * CV_ + wid * 64) * M_;
    for (int ms = 0; ms < 64; ++ms) {
        const int idx = (lq * 2048 + ms * 32 + 8 * g) ^ swz;
        f16x8 A = *reinterpret_cast<f16x8*>(&P[idx]);  // P[q=lq][m = 32ms+8g+i]
#pragma unroll
        for (int vt = 0; vt < 4; ++vt) {
            const f16* vr = gb + (size_t)(vt * 16 + lq) * M_ + ms * 32 + 8 * g;
            f16x8 Bv = *reinterpret_cast<const f16x8*>(vr);  // V[m][v=.. lq]
            acc[vt] = MFMA16(A, Bv, acc[vt]);  // O[q=4g+r][v]
        }
    }
    float li[4];
#pragma unroll
    for (int r = 0; r < 4; ++r) li[r] = linv[4 * g + r];
#pragma unroll
    for (int vt = 0; vt < 4; ++vt)
#pragma unroll
        for (int r = 0; r < 4; ++r)
            o_inT[((size_t)b * L_ + q0 + 4 * g + r) * CV_ + wid * 64 + vt * 16 + lq] =
                (f16)(acc[vt][r] * li[r]);
}

// ---------------------------------------------------------------------------
// Kernel C: MFMA output projection + residual.
//   out[b,oc,l] = gamma * sum_v Wo[oc,v] * o_inT[b,l,v] + x[b,oc,l]
//   Block = 64oc x 64l; wave owns 16 oc x 64 l (4 l-tiles).
// ---------------------------------------------------------------------------
__global__ __launch_bounds__(256) void out_mfma(const f16* __restrict__ Wo_h,
                                                const f16* __restrict__ o_inT,
                                                const float* __restrict__ x,
                                                const float* __restrict__ gamma_p,
                                                float* __restrict__ out) {
    const int b    = blockIdx.z;
    const int l0   = blockIdx.x * 64;
    const int wid  = threadIdx.x >> 6;
    const int oc0  = blockIdx.y * 64 + wid * 16;
    const int lane = threadIdx.x & 63;
    const int lq   = lane & 15;
    const int g    = lane >> 4;

    f32x4 acc[4] = {{0.f, 0.f, 0.f, 0.f}, {0.f, 0.f, 0.f, 0.f},
                    {0.f, 0.f, 0.f, 0.f}, {0.f, 0.f, 0.f, 0.f}};
    const f16* ap = Wo_h + (size_t)(oc0 + lq) * CV_;
#pragma unroll
    for (int ks = 0; ks < 8; ++ks) {
        f16x8 A = *reinterpret_cast<const f16x8*>(ap + ks * 32 + 8 * g);  // Wo[oc=lq][v]
#pragma unroll
        for (int lt = 0; lt < 4; ++lt) {
            const f16* bp = o_inT + ((size_t)b * L_ + l0 + lt * 16 + lq) * CV_ + ks * 32 + 8 * g;
            acc[lt] = MFMA16(A, *reinterpret_cast<const f16x8*>(bp), acc[lt]);
        }
    }
    const float gamma = *gamma_p;
#pragma unroll
    for (int lt = 0; lt < 4; ++lt)
#pragma unroll
        for (int r = 0; r < 4; ++r) {
            const size_t o = ((size_t)b * C_ + oc0 + 4 * g + r) * L_ + l0 + lt * 16 + lq;
            out[o] = fmaf(gamma, acc[lt][r], x[o]);
        }
}

// ---------------------------------------------------------------------------
extern "C" void kernel_launch(void* const* d_in, const int* in_sizes, int n_in,
                              void* d_out, int out_size, void* d_ws, size_t ws_size,
                              hipStream_t stream) {
    const float* x       = (const float*)d_in[0];
    const float* W_theta = (const float*)d_in[1];
    const float* W_phi   = (const float*)d_in[2];
    const float* W_g     = (const float*)d_in[3];
    const float* W_o     = (const float*)d_in[4];
    const float* gamma   = (const float*)d_in[5];
    float* out = (float*)d_out;

    // workspace carve (f16): thetaT | phiT | g | o_inT | Wo_h  ~= 31 MiB
    f16* thetaT = (f16*)d_ws;                          // [B][L][CK]
    f16* phiT   = thetaT + (size_t)B_ * L_ * CK_;      // [B][M][CK]
    f16* g_h    = phiT + (size_t)B_ * M_ * CK_;        // [B][CV][M]
    f16* o_inT  = g_h + (size_t)B_ * CV_ * M_;         // [B][L][CV]
    f16* Wo_h   = o_inT + (size_t)B_ * L_ * CV_;       // [C][CV]

    cvt_kernel<<<dim3((C_ * CV_) / 256), 256, 0, stream>>>(W_o, Wo_h, C_ * CV_);
    proj_kernel<0, 1><<<dim3(L_ / 256, CK_ / 16, B_), 256, 0, stream>>>(W_theta, x, thetaT, CK_);
    proj_kernel<1, 1><<<dim3(M_ / 256, CK_ / 16, B_), 256, 0, stream>>>(W_phi, x, phiT, CK_);
    proj_kernel<1, 0><<<dim3(M_ / 256, CV_ / 16, B_), 256, 0, stream>>>(W_g, x, g_h, CV_);
    attn_mfma<<<dim3(L_ / 16, B_), 256, 0, stream>>>(thetaT, phiT, g_h, o_inT);
    out_mfma<<<dim3(L_ / 64, C_ / 64, B_), 256, 0, stream>>>(Wo_h, o_inT, x, gamma, out);
}

// Round 4
// 541.454 us; speedup vs baseline: 2.0228x; 1.2001x over previous
//
#include <hip/hip_runtime.h>
#include <cstdint>
#include <cstddef>

// Problem constants
#define B_ 8
#define C_ 512
#define L_ 4096
#define M_ 2048   // L/2 (pooled keys)
#define CK_ 64    // C/8
#define CV_ 256   // C/2

typedef _Float16 f16;
typedef _Float16 f16x8 __attribute__((ext_vector_type(8)));
typedef _Float16 f16x4 __attribute__((ext_vector_type(4)));
typedef _Float16 f16x2 __attribute__((ext_vector_type(2)));
typedef float f32x4 __attribute__((ext_vector_type(4)));
typedef float f32x16 __attribute__((ext_vector_type(16)));
typedef unsigned int u32x4 __attribute__((ext_vector_type(4)));

#define MFMA16(A, Bv, Cv) __builtin_amdgcn_mfma_f32_16x16x32_f16(A, Bv, Cv, 0, 0, 0)
#define MFMA32(A, Bv, Cv) __builtin_amdgcn_mfma_f32_32x32x16_f16(A, Bv, Cv, 0, 0, 0)

// ---------------------------------------------------------------------------
// Kernel A: channel projection (fp32 math, f16 output in MFMA layout)
//   POOL=1: maxpool2 over last axis. TRANS=1: write out[b,j,k] (seq-major).
// ---------------------------------------------------------------------------
template <int POOL, int TRANS>
__global__ __launch_bounds__(256) void proj_kernel(const float* __restrict__ W,
                                                   const float* __restrict__ x,
                                                   f16* __restrict__ out,
                                                   int K) {
    __shared__ float wsm[16][C_];  // 32 KB
    const int b  = blockIdx.z;
    const int k0 = blockIdx.y * 16;
    const int t  = threadIdx.x;
    const int j  = blockIdx.x * 256 + t;

#pragma unroll
    for (int i = 0; i < 32; ++i) {
        int f = i * 256 + t;
        wsm[f >> 9][f & 511] = W[(size_t)(k0 + (f >> 9)) * C_ + (f & 511)];
    }
    __syncthreads();

    const float* xb = x + (size_t)b * C_ * L_;
    float a0[16];
#pragma unroll
    for (int kk = 0; kk < 16; ++kk) a0[kk] = 0.f;

    if (POOL) {
        float a1[16];
#pragma unroll
        for (int kk = 0; kk < 16; ++kk) a1[kk] = 0.f;
        for (int c = 0; c < C_; ++c) {
            float2 v = *reinterpret_cast<const float2*>(xb + (size_t)c * L_ + 2 * j);
#pragma unroll
            for (int kk = 0; kk < 16; ++kk) {
                float w = wsm[kk][c];
                a0[kk] = fmaf(w, v.x, a0[kk]);
                a1[kk] = fmaf(w, v.y, a1[kk]);
            }
        }
#pragma unroll
        for (int kk = 0; kk < 16; ++kk) a0[kk] = fmaxf(a0[kk], a1[kk]);
    } else {
        for (int c = 0; c < C_; ++c) {
            float v = xb[(size_t)c * L_ + j];
#pragma unroll
            for (int kk = 0; kk < 16; ++kk) a0[kk] = fmaf(wsm[kk][c], v, a0[kk]);
        }
    }

    const int Lout = POOL ? M_ : L_;
    if (TRANS) {
        f16* op = out + ((size_t)b * Lout + j) * K + k0;
        f16x8 v0, v1;
#pragma unroll
        for (int kk = 0; kk < 8; ++kk) { v0[kk] = (f16)a0[kk]; v1[kk] = (f16)a0[kk + 8]; }
        *reinterpret_cast<f16x8*>(op)     = v0;
        *reinterpret_cast<f16x8*>(op + 8) = v1;
    } else {
#pragma unroll
        for (int kk = 0; kk < 16; ++kk)
            out[((size_t)b * K + k0 + kk) * Lout + j] = (f16)a0[kk];
    }
}

// ---------------------------------------------------------------------------
// Kernel W: fp32 -> f16 convert for W_o
// ---------------------------------------------------------------------------
__global__ __launch_bounds__(256) void cvt_kernel(const float* __restrict__ in,
                                                  f16* __restrict__ out, int n) {
    int i = blockIdx.x * 256 + threadIdx.x;
    if (i < n) out[i] = (f16)in[i];
}

// ---------------------------------------------------------------------------
// Kernel B: flash attention, zero LDS / zero barriers.
//   Block = 256 thr = 4 warps; warp = (q-group of 32, v-half of 128).
//   Per 32-m step: Sᵀ = mfma32(K,Q) (col=q lane-local) -> per-lane online
//   softmax (defer-max THR=8) -> cvt_pkrtz + permlane32_swap to build PV
//   B-frags -> acc += mfma32(Vᵀ, P). Normalize + store in epilogue.
//   permlane32_swap: vdst.high32 <-> vsrc.low32, so vdst = LOW-m-half pair,
//   vsrc = HIGH-m-half pair (T12 convention).
// ---------------------------------------------------------------------------
__global__ __launch_bounds__(256) void attn_flash(const f16* __restrict__ thetaT,
                                                  const f16* __restrict__ phiT,
                                                  const f16* __restrict__ gh,
                                                  f16* __restrict__ o_inT) {
    const int bid = blockIdx.x;
    const int swz = (bid & 7) * 64 + (bid >> 3);  // XCD-major: batch = bid&7
    const int b   = swz >> 6;
    const int qt  = swz & 63;
    const int w   = threadIdx.x >> 6;
    const int qg  = w >> 1;
    const int vh  = w & 1;
    const int q0  = qt * 64 + qg * 32;     // 32 queries for this warp
    const int vb  = vh * 128;              // 128 v-rows for this warp
    const int lane = threadIdx.x & 63;
    const int lq   = lane & 31;            // query col / v row
    const int hi   = lane >> 5;

    // Q fragments (B-operand): Q[q=lq][ck = f*16 + hi*8 + i]
    const f16* qp = thetaT + ((size_t)b * L_ + q0 + lq) * CK_ + hi * 8;
    f16x8 Qf[4];
#pragma unroll
    for (int f = 0; f < 4; ++f) Qf[f] = *reinterpret_cast<const f16x8*>(qp + f * 16);

    f32x16 acc[4] = {};
    float m_run = -3.0e38f;
    float l_run = 0.f;

    const f16* kbase = phiT + ((size_t)b * M_ + lq) * CK_ + hi * 8;
    const f16* vbase_p = gh + ((size_t)b * CV_ + vb + lq) * M_ + hi * 8;

    for (int m0 = 0; m0 < M_; m0 += 32) {
        // ---- issue all loads for this step up front ----
        const f16* kp = kbase + (size_t)m0 * CK_;
        f16x8 Kf[4];
#pragma unroll
        for (int f = 0; f < 4; ++f) Kf[f] = *reinterpret_cast<const f16x8*>(kp + f * 16);
        f16x8 Vf[2][4];
#pragma unroll
        for (int ch = 0; ch < 2; ++ch)
#pragma unroll
            for (int vt = 0; vt < 4; ++vt)
                Vf[ch][vt] = *reinterpret_cast<const f16x8*>(
                    vbase_p + (size_t)(vt * 32) * M_ + m0 + ch * 16);

        // ---- QK^T: S^T[m][q], col = q = lq ----
        f32x16 S = {};
#pragma unroll
        for (int f = 0; f < 4; ++f) S = MFMA32(Kf[f], Qf[f], S);

        float s[16];
#pragma unroll
        for (int r = 0; r < 16; ++r) s[r] = S[r];

        // ---- online softmax (per-lane; q is lane-local) ----
        float tm = s[0];
#pragma unroll
        for (int r = 1; r < 16; ++r) tm = fmaxf(tm, s[r]);
        tm = fmaxf(tm, __shfl_xor(tm, 32));
        if (tm > m_run + 8.f) {  // defer-max: rescale only on big growth
            float sc = __expf(m_run - tm);
#pragma unroll
            for (int vt = 0; vt < 4; ++vt)
#pragma unroll
                for (int r = 0; r < 16; ++r) acc[vt][r] *= sc;
            l_run *= sc;
            m_run = tm;
        }
        float ls = 0.f;
#pragma unroll
        for (int r = 0; r < 16; ++r) {
            s[r] = __expf(s[r] - m_run);
            ls += s[r];
        }
        l_run += ls + __shfl_xor(ls, 32);

        // ---- P -> f16 B-fragments via cvt_pkrtz + permlane32_swap ----
        // pk[i] = pack(s[2i], s[2i+1]); before swap, lane half hi holds
        // m-pairs: pk0=(0,1|4,5) pk1=(2,3|6,7) pk2=(8,9|12,13) pk3=(10,11|14,15)
        // swap(vdst=low-half pair, vsrc=high-half pair):
        //   vdst_new = {vdst.low, vsrc.low}, vsrc_new = {vdst.high, vsrc.high}
        uint32_t pk[8];
#pragma unroll
        for (int i = 0; i < 8; ++i)
            pk[i] = __builtin_bit_cast(uint32_t,
                        __builtin_amdgcn_cvt_pkrtz(s[2 * i], s[2 * i + 1]));
        asm volatile("v_permlane32_swap_b32 %0, %1" : "+v"(pk[0]), "+v"(pk[2]));
        asm volatile("v_permlane32_swap_b32 %0, %1" : "+v"(pk[1]), "+v"(pk[3]));
        asm volatile("v_permlane32_swap_b32 %0, %1" : "+v"(pk[4]), "+v"(pk[6]));
        asm volatile("v_permlane32_swap_b32 %0, %1" : "+v"(pk[5]), "+v"(pk[7]));
        u32x4 fr0 = {pk[0], pk[1], pk[2], pk[3]};
        u32x4 fr1 = {pk[4], pk[5], pk[6], pk[7]};
        f16x8 P0 = __builtin_bit_cast(f16x8, fr0);
        f16x8 P1 = __builtin_bit_cast(f16x8, fr1);

        // ---- PV: acc[vt] += V^T-frag x P-frag ----
#pragma unroll
        for (int vt = 0; vt < 4; ++vt) acc[vt] = MFMA32(Vf[0][vt], P0, acc[vt]);
#pragma unroll
        for (int vt = 0; vt < 4; ++vt) acc[vt] = MFMA32(Vf[1][vt], P1, acc[vt]);
    }

    // ---- epilogue: normalize, store o_inT[b][q][v] ----
    const float inv = 1.f / l_run;
    f16* op = o_inT + ((size_t)b * L_ + q0 + lq) * CV_ + vb + 4 * hi;
#pragma unroll
    for (int vt = 0; vt < 4; ++vt)
#pragma unroll
        for (int rq = 0; rq < 4; ++rq) {
            f16x4 o;
#pragma unroll
            for (int j = 0; j < 4; ++j) o[j] = (f16)(acc[vt][4 * rq + j] * inv);
            *reinterpret_cast<f16x4*>(op + vt * 32 + 8 * rq) = o;
        }
}

// ---------------------------------------------------------------------------
// Kernel C: MFMA output projection + residual.
// ---------------------------------------------------------------------------
__global__ __launch_bounds__(256) void out_mfma(const f16* __restrict__ Wo_h,
                                                const f16* __restrict__ o_inT,
                                                const float* __restrict__ x,
                                                const float* __restrict__ gamma_p,
                                                float* __restrict__ out) {
    const int b    = blockIdx.z;
    const int l0   = blockIdx.x * 64;
    const int wid  = threadIdx.x >> 6;
    const int oc0  = blockIdx.y * 64 + wid * 16;
    const int lane = threadIdx.x & 63;
    const int lq   = lane & 15;
    const int g    = lane >> 4;

    f32x4 acc[4] = {{0.f, 0.f, 0.f, 0.f}, {0.f, 0.f, 0.f, 0.f},
                    {0.f, 0.f, 0.f, 0.f}, {0.f, 0.f, 0.f, 0.f}};
    const f16* ap = Wo_h + (size_t)(oc0 + lq) * CV_;
#pragma unroll
    for (int ks = 0; ks < 8; ++ks) {
        f16x8 A = *reinterpret_cast<const f16x8*>(ap + ks * 32 + 8 * g);
#pragma unroll
        for (int lt = 0; lt < 4; ++lt) {
            const f16* bp = o_inT + ((size_t)b * L_ + l0 + lt * 16 + lq) * CV_ + ks * 32 + 8 * g;
            acc[lt] = MFMA16(A, *reinterpret_cast<const f16x8*>(bp), acc[lt]);
        }
    }
    const float gamma = *gamma_p;
#pragma unroll
    for (int lt = 0; lt < 4; ++lt)
#pragma unroll
        for (int r = 0; r < 4; ++r) {
            const size_t o = ((size_t)b * C_ + oc0 + 4 * g + r) * L_ + l0 + lt * 16 + lq;
            out[o] = fmaf(gamma, acc[lt][r], x[o]);
        }
}

// ---------------------------------------------------------------------------
extern "C" void kernel_launch(void* const* d_in, const int* in_sizes, int n_in,
                              void* d_out, int out_size, void* d_ws, size_t ws_size,
                              hipStream_t stream) {
    const float* x       = (const float*)d_in[0];
    const float* W_theta = (const float*)d_in[1];
    const float* W_phi   = (const float*)d_in[2];
    const float* W_g     = (const float*)d_in[3];
    const float* W_o     = (const float*)d_in[4];
    const float* gamma   = (const float*)d_in[5];
    float* out = (float*)d_out;

    // workspace carve (f16): thetaT | phiT | g | o_inT | Wo_h  ~= 31 MiB
    f16* thetaT = (f16*)d_ws;                          // [B][L][CK]
    f16* phiT   = thetaT + (size_t)B_ * L_ * CK_;      // [B][M][CK]
    f16* g_h    = phiT + (size_t)B_ * M_ * CK_;        // [B][CV][M]
    f16* o_inT  = g_h + (size_t)B_ * CV_ * M_;         // [B][L][CV]
    f16* Wo_h   = o_inT + (size_t)B_ * L_ * CV_;       // [C][CV]

    cvt_kernel<<<dim3((C_ * CV_) / 256), 256, 0, stream>>>(W_o, Wo_h, C_ * CV_);
    proj_kernel<0, 1><<<dim3(L_ / 256, CK_ / 16, B_), 256, 0, stream>>>(W_theta, x, thetaT, CK_);
    proj_kernel<1, 1><<<dim3(M_ / 256, CK_ / 16, B_), 256, 0, stream>>>(W_phi, x, phiT, CK_);
    proj_kernel<1, 0><<<dim3(M_ / 256, CV_ / 16, B_), 256, 0, stream>>>(W_g, x, g_h, CV_);
    attn_flash<<<dim3(512), 256, 0, stream>>>(thetaT, phiT, g_h, o_inT);
    out_mfma<<<dim3(L_ / 64, C_ / 64, B_), 256, 0, stream>>>(Wo_h, o_inT, x, gamma, out);
}

// Round 5
// 256.818 us; speedup vs baseline: 4.2648x; 2.1083x over previous
//
#include <hip/hip_runtime.h>
#include <cstdint>
#include <cstddef>

// Problem constants
#define B_ 8
#define C_ 512
#define L_ 4096
#define M_ 2048   // L/2 (pooled keys)
#define CK_ 64    // C/8
#define CV_ 256   // C/2

typedef _Float16 f16;
typedef _Float16 f16x8 __attribute__((ext_vector_type(8)));
typedef _Float16 f16x4 __attribute__((ext_vector_type(4)));
typedef float f32x4 __attribute__((ext_vector_type(4)));
typedef float f32x16 __attribute__((ext_vector_type(16)));
typedef unsigned int u32x4 __attribute__((ext_vector_type(4)));

#define MFMA16(A, Bv, Cv) __builtin_amdgcn_mfma_f32_16x16x32_f16(A, Bv, Cv, 0, 0, 0)
#define MFMA32(A, Bv, Cv) __builtin_amdgcn_mfma_f32_32x32x16_f16(A, Bv, Cv, 0, 0, 0)

static __device__ __forceinline__ uint32_t pkrtz(float a, float b) {
    return __builtin_bit_cast(uint32_t, __builtin_amdgcn_cvt_pkrtz(a, b));
}

// ---------------------------------------------------------------------------
// Fused projection kernel (MFMA f16, fp32 accum).
//   Computes all 384 output channels (theta 64 | phi 64 | g 256) for a
//   32-l tile, K=C=512.  A = W rows (contig fp32 -> f16 pack);
//   B = x columns (8 stride-L dword loads, packed in-register).
//   phi/g are maxpool2'd over l via shfl_xor(1) on D cols (col = lane).
//   Outputs in fragment-native layouts:
//     theta2[b][ck>>3][l][8]   phi2[b][ck>>3][m][8]   g2[b][m>>3][v][8]
// ---------------------------------------------------------------------------
__global__ __launch_bounds__(256) void fused_proj(const float* __restrict__ Wt,
                                                  const float* __restrict__ Wp,
                                                  const float* __restrict__ Wg,
                                                  const float* __restrict__ x,
                                                  f16* __restrict__ theta2,
                                                  f16* __restrict__ phi2,
                                                  f16* __restrict__ g2) {
    const int b    = blockIdx.y;
    const int l0   = blockIdx.x * 32;
    const int w    = threadIdx.x >> 6;   // warp: och range [w*96, w*96+96)
    const int lane = threadIdx.x & 63;
    const int lq   = lane & 15;
    const int g    = lane >> 4;
    const int wb   = w * 96;

    f32x4 acc[6][2] = {};

    const float* xb = x + (size_t)b * C_ * L_;
    for (int ks = 0; ks < 16; ++ks) {
        const int c0 = ks * 32;
        // B fragments: x[c0+8g+i][l0 + lt*16 + lq]
        f16x8 Bf[2];
#pragma unroll
        for (int lt = 0; lt < 2; ++lt) {
            float v[8];
#pragma unroll
            for (int i = 0; i < 8; ++i)
                v[i] = xb[(size_t)(c0 + 8 * g + i) * L_ + l0 + lt * 16 + lq];
            u32x4 p = {pkrtz(v[0], v[1]), pkrtz(v[2], v[3]),
                       pkrtz(v[4], v[5]), pkrtz(v[6], v[7])};
            Bf[lt] = __builtin_bit_cast(f16x8, p);
        }
        // A fragments + MFMA per och-tile
#pragma unroll
        for (int t = 0; t < 6; ++t) {
            const int och0 = wb + t * 16;
            const float* wsrc;
            int row;
            if (och0 < 64)       { wsrc = Wt; row = och0; }
            else if (och0 < 128) { wsrc = Wp; row = och0 - 64; }
            else                 { wsrc = Wg; row = och0 - 128; }
            const float* ap = wsrc + (size_t)(row + lq) * C_ + c0 + 8 * g;
            float4 w0 = *reinterpret_cast<const float4*>(ap);
            float4 w1 = *reinterpret_cast<const float4*>(ap + 4);
            u32x4 p = {pkrtz(w0.x, w0.y), pkrtz(w0.z, w0.w),
                       pkrtz(w1.x, w1.y), pkrtz(w1.z, w1.w)};
            f16x8 Af = __builtin_bit_cast(f16x8, p);
            acc[t][0] = MFMA16(Af, Bf[0], acc[t][0]);
            acc[t][1] = MFMA16(Af, Bf[1], acc[t][1]);
        }
    }

    // Epilogue. D layout (MFMA16): row = 4g + r (och), col = lq (l).
#pragma unroll
    for (int t = 0; t < 6; ++t) {
        const int och0 = wb + t * 16;
#pragma unroll
        for (int lt = 0; lt < 2; ++lt) {
            const int l = l0 + lt * 16 + lq;
            if (och0 < 64) {
#pragma unroll
                for (int r = 0; r < 4; ++r) {
                    const int och = och0 + 4 * g + r;
                    theta2[(((size_t)b * 8 + (och >> 3)) * L_ + l) * 8 + (och & 7)] =
                        (f16)acc[t][lt][r];
                }
            } else {
#pragma unroll
                for (int r = 0; r < 4; ++r) {
                    const float pv = fmaxf(acc[t][lt][r], __shfl_xor(acc[t][lt][r], 1));
                    if (!(lane & 1)) {
                        const int m = l >> 1;
                        if (och0 < 128) {
                            const int kc = och0 - 64 + 4 * g + r;
                            phi2[(((size_t)b * 8 + (kc >> 3)) * M_ + m) * 8 + (kc & 7)] =
                                (f16)pv;
                        } else {
                            const int vc = och0 - 128 + 4 * g + r;
                            g2[(((size_t)b * 256 + (m >> 3)) * CV_ + vc) * 8 + (m & 7)] =
                                (f16)pv;
                        }
                    }
                }
            }
        }
    }
}

// ---------------------------------------------------------------------------
// Kernel W: fp32 -> f16 convert for W_o
// ---------------------------------------------------------------------------
__global__ __launch_bounds__(256) void cvt_kernel(const float* __restrict__ in,
                                                  f16* __restrict__ out, int n) {
    int i = blockIdx.x * 256 + threadIdx.x;
    if (i < n) out[i] = (f16)in[i];
}

// ---------------------------------------------------------------------------
// Kernel B: flash attention, zero LDS / zero barriers.
//   Same structure as round 4 (verified) but all Q/K/V fragment loads now
//   hit the fragment-native layouts -> lane-stride 16B, fully coalesced.
// ---------------------------------------------------------------------------
__global__ __launch_bounds__(256) void attn_flash(const f16* __restrict__ theta2,
                                                  const f16* __restrict__ phi2,
                                                  const f16* __restrict__ g2,
                                                  f16* __restrict__ o_inT) {
    const int bid = blockIdx.x;
    const int swz = (bid & 7) * 64 + (bid >> 3);  // XCD-major: batch = bid&7
    const int b   = swz >> 6;
    const int qt  = swz & 63;
    const int w   = threadIdx.x >> 6;
    const int qg  = w >> 1;
    const int vh  = w & 1;
    const int q0  = qt * 64 + qg * 32;     // 32 queries for this warp
    const int vb  = vh * 128;              // 128 v-rows for this warp
    const int lane = threadIdx.x & 63;
    const int lq   = lane & 31;
    const int hi   = lane >> 5;

    // Q fragments (B-operand): Q[q=lq][ck = 16f + 8hi + i]
    const f16* qbase = theta2 + (size_t)b * 8 * L_ * 8;
    f16x8 Qf[4];
#pragma unroll
    for (int f = 0; f < 4; ++f)
        Qf[f] = *reinterpret_cast<const f16x8*>(
            qbase + ((size_t)(2 * f + hi) * L_ + q0 + lq) * 8);

    f32x16 acc[4] = {};
    float m_run = -3.0e38f;
    float l_run = 0.f;

    const f16* kbase = phi2 + (size_t)b * 8 * M_ * 8;
    const f16* vbase = g2 + (size_t)b * 256 * CV_ * 8;

    for (int m0 = 0; m0 < M_; m0 += 32) {
        // ---- loads for this step up front (all coalesced) ----
        f16x8 Kf[4];
#pragma unroll
        for (int f = 0; f < 4; ++f)
            Kf[f] = *reinterpret_cast<const f16x8*>(
                kbase + ((size_t)(2 * f + hi) * M_ + m0 + lq) * 8);
        f16x8 Vf[2][4];
#pragma unroll
        for (int ch = 0; ch < 2; ++ch)
#pragma unroll
            for (int vt = 0; vt < 4; ++vt)
                Vf[ch][vt] = *reinterpret_cast<const f16x8*>(
                    vbase + ((size_t)((m0 >> 3) + 2 * ch + hi) * CV_ +
                             vb + vt * 32 + lq) * 8);

        // ---- QK^T: S^T[m][q], col = q = lq ----
        f32x16 S = {};
#pragma unroll
        for (int f = 0; f < 4; ++f) S = MFMA32(Kf[f], Qf[f], S);

        float s[16];
#pragma unroll
        for (int r = 0; r < 16; ++r) s[r] = S[r];

        // ---- online softmax (per-lane; q is lane-local) ----
        float tm = s[0];
#pragma unroll
        for (int r = 1; r < 16; ++r) tm = fmaxf(tm, s[r]);
        tm = fmaxf(tm, __shfl_xor(tm, 32));
        if (tm > m_run + 8.f) {  // defer-max
            float sc = __expf(m_run - tm);
#pragma unroll
            for (int vt = 0; vt < 4; ++vt)
#pragma unroll
                for (int r = 0; r < 16; ++r) acc[vt][r] *= sc;
            l_run *= sc;
            m_run = tm;
        }
        float ls = 0.f;
#pragma unroll
        for (int r = 0; r < 16; ++r) {
            s[r] = __expf(s[r] - m_run);
            ls += s[r];
        }
        l_run += ls + __shfl_xor(ls, 32);

        // ---- P -> f16 B-fragments (cvt_pkrtz + permlane32_swap, T12) ----
        uint32_t pk[8];
#pragma unroll
        for (int i = 0; i < 8; ++i) pk[i] = pkrtz(s[2 * i], s[2 * i + 1]);
        asm volatile("v_permlane32_swap_b32 %0, %1" : "+v"(pk[0]), "+v"(pk[2]));
        asm volatile("v_permlane32_swap_b32 %0, %1" : "+v"(pk[1]), "+v"(pk[3]));
        asm volatile("v_permlane32_swap_b32 %0, %1" : "+v"(pk[4]), "+v"(pk[6]));
        asm volatile("v_permlane32_swap_b32 %0, %1" : "+v"(pk[5]), "+v"(pk[7]));
        u32x4 fr0 = {pk[0], pk[1], pk[2], pk[3]};
        u32x4 fr1 = {pk[4], pk[5], pk[6], pk[7]};
        f16x8 P0 = __builtin_bit_cast(f16x8, fr0);
        f16x8 P1 = __builtin_bit_cast(f16x8, fr1);

        // ---- PV ----
#pragma unroll
        for (int vt = 0; vt < 4; ++vt) acc[vt] = MFMA32(Vf[0][vt], P0, acc[vt]);
#pragma unroll
        for (int vt = 0; vt < 4; ++vt) acc[vt] = MFMA32(Vf[1][vt], P1, acc[vt]);
    }

    // ---- epilogue: normalize, store o_inT[b][q][v] ----
    const float inv = 1.f / l_run;
    f16* op = o_inT + ((size_t)b * L_ + q0 + lq) * CV_ + vb + 4 * hi;
#pragma unroll
    for (int vt = 0; vt < 4; ++vt)
#pragma unroll
        for (int rq = 0; rq < 4; ++rq) {
            f16x4 o;
#pragma unroll
            for (int j = 0; j < 4; ++j) o[j] = (f16)(acc[vt][4 * rq + j] * inv);
            *reinterpret_cast<f16x4*>(op + vt * 32 + 8 * rq) = o;
        }
}

// ---------------------------------------------------------------------------
// Kernel C: MFMA output projection + residual.
// ---------------------------------------------------------------------------
__global__ __launch_bounds__(256) void out_mfma(const f16* __restrict__ Wo_h,
                                                const f16* __restrict__ o_inT,
                                                const float* __restrict__ x,
                                                const float* __restrict__ gamma_p,
                                                float* __restrict__ out) {
    const int b    = blockIdx.z;
    const int l0   = blockIdx.x * 64;
    const int wid  = threadIdx.x >> 6;
    const int oc0  = blockIdx.y * 64 + wid * 16;
    const int lane = threadIdx.x & 63;
    const int lq   = lane & 15;
    const int g    = lane >> 4;

    f32x4 acc[4] = {{0.f, 0.f, 0.f, 0.f}, {0.f, 0.f, 0.f, 0.f},
                    {0.f, 0.f, 0.f, 0.f}, {0.f, 0.f, 0.f, 0.f}};
    const f16* ap = Wo_h + (size_t)(oc0 + lq) * CV_;
#pragma unroll
    for (int ks = 0; ks < 8; ++ks) {
        f16x8 A = *reinterpret_cast<const f16x8*>(ap + ks * 32 + 8 * g);
#pragma unroll
        for (int lt = 0; lt < 4; ++lt) {
            const f16* bp = o_inT + ((size_t)b * L_ + l0 + lt * 16 + lq) * CV_ + ks * 32 + 8 * g;
            acc[lt] = MFMA16(A, *reinterpret_cast<const f16x8*>(bp), acc[lt]);
        }
    }
    const float gamma = *gamma_p;
#pragma unroll
    for (int lt = 0; lt < 4; ++lt)
#pragma unroll
        for (int r = 0; r < 4; ++r) {
            const size_t o = ((size_t)b * C_ + oc0 + 4 * g + r) * L_ + l0 + lt * 16 + lq;
            out[o] = fmaf(gamma, acc[lt][r], x[o]);
        }
}

// ---------------------------------------------------------------------------
extern "C" void kernel_launch(void* const* d_in, const int* in_sizes, int n_in,
                              void* d_out, int out_size, void* d_ws, size_t ws_size,
                              hipStream_t stream) {
    const float* x       = (const float*)d_in[0];
    const float* W_theta = (const float*)d_in[1];
    const float* W_phi   = (const float*)d_in[2];
    const float* W_g     = (const float*)d_in[3];
    const float* W_o     = (const float*)d_in[4];
    const float* gamma   = (const float*)d_in[5];
    float* out = (float*)d_out;

    // workspace carve (f16): theta2 | phi2 | g2 | o_inT | Wo_h ~= 30.25 MiB
    f16* theta2 = (f16*)d_ws;                          // [B][8][L][8]
    f16* phi2   = theta2 + (size_t)B_ * 8 * L_ * 8;    // [B][8][M][8]
    f16* g2     = phi2 + (size_t)B_ * 8 * M_ * 8;      // [B][256][CV][8]
    f16* o_inT  = g2 + (size_t)B_ * 256 * CV_ * 8;     // [B][L][CV]
    f16* Wo_h   = o_inT + (size_t)B_ * L_ * CV_;       // [C][CV]

    cvt_kernel<<<dim3((C_ * CV_) / 256), 256, 0, stream>>>(W_o, Wo_h, C_ * CV_);
    fused_proj<<<dim3(L_ / 32, B_), 256, 0, stream>>>(W_theta, W_phi, W_g, x,
                                                      theta2, phi2, g2);
    attn_flash<<<dim3(512), 256, 0, stream>>>(theta2, phi2, g2, o_inT);
    out_mfma<<<dim3(L_ / 64, C_ / 64, B_), 256, 0, stream>>>(Wo_h, o_inT, x, gamma, out);
}